// Round 1
// baseline (1210.482 us; speedup 1.0000x reference)
//
#include <hip/hip_runtime.h>
#include <hip/hip_bf16.h>

// B=8, C=512, G=32, HW=4096. All matrix dims are multiples of 128 -> no guards.
typedef __attribute__((ext_vector_type(8))) short short8;
typedef __attribute__((ext_vector_type(4))) float f32x4;

#define ALPHA 0.044194173824159216f

__device__ __forceinline__ unsigned short f2bf(float f) {
    union { float f; unsigned int u; } c; c.f = f;
    unsigned int u = c.u;
    return (unsigned short)((u + 0x7FFFu + ((u >> 16) & 1u)) >> 16);
}

// ---------------- GroupNorm stats: one block per (b,g), 16ch x 4096 contiguous ----
__global__ __launch_bounds__(256) void gn_stats(const float* __restrict__ x,
                                                float* __restrict__ stats) {
    int blk = blockIdx.x;  // b*32 + g
    const float4* src = (const float4*)(x + (size_t)blk * 65536);
    float s = 0.f, sq = 0.f;
    for (int i = threadIdx.x; i < 16384; i += 256) {
        float4 v = src[i];
        s  += v.x + v.y + v.z + v.w;
        sq += v.x*v.x + v.y*v.y + v.z*v.z + v.w*v.w;
    }
    for (int off = 32; off; off >>= 1) {
        s  += __shfl_down(s, off);
        sq += __shfl_down(sq, off);
    }
    __shared__ float ss[4], ssq[4];
    int wid = threadIdx.x >> 6;
    if ((threadIdx.x & 63) == 0) { ss[wid] = s; ssq[wid] = sq; }
    __syncthreads();
    if (threadIdx.x == 0) {
        float S = ss[0]+ss[1]+ss[2]+ss[3], Q = ssq[0]+ssq[1]+ssq[2]+ssq[3];
        float mu = S * (1.f/65536.f);
        float var = Q * (1.f/65536.f) - mu*mu;
        stats[blk] = mu;
        stats[256 + blk] = rsqrtf(var + 1e-6f);
    }
}

// ---------------- weight fp32 -> bf16 ----------------
__global__ __launch_bounds__(256) void wcvt(const float* __restrict__ s,
                                            unsigned short* __restrict__ d) {
    int i = blockIdx.x * 1024 + threadIdx.x * 4;
    float4 v = *(const float4*)(s + i);
    ushort4 o = make_ushort4(f2bf(v.x), f2bf(v.y), f2bf(v.z), f2bf(v.w));
    *(ushort4*)(d + i) = o;
}

// ------- GN apply + transpose: x[b][c][hw] fp32 -> h[(b*4096+hw)][c] bf16 -------
__global__ __launch_bounds__(256) void gn_apply(const float* __restrict__ x,
                                                const float* __restrict__ stats,
                                                const float* __restrict__ gamma,
                                                const float* __restrict__ beta,
                                                unsigned short* __restrict__ h) {
    __shared__ unsigned short t[64][72];  // [hw_local][c_local], pad 72 (144B rows)
    int b = blockIdx.z, c0 = blockIdx.y * 64, hw0 = blockIdx.x * 64;
    int tid = threadIdx.x;
#pragma unroll
    for (int rep = 0; rep < 4; ++rep) {
        int lin = rep * 256 + tid;         // 1024 = 64 c-rows x 16 float4
        int row = lin >> 4;                // c_local
        int c4  = lin & 15;                // float4 idx along hw
        int c   = c0 + row;
        const float4* src = (const float4*)(x + ((size_t)(b*512 + c) << 12) + hw0);
        float4 v = src[c4];
        int sidx = b*32 + (c >> 4);
        float mu = stats[sidx], rs = stats[256 + sidx];
        float ga = gamma[c] * rs, be = beta[c] - mu * ga;
        t[c4*4+0][row] = f2bf(v.x * ga + be);
        t[c4*4+1][row] = f2bf(v.y * ga + be);
        t[c4*4+2][row] = f2bf(v.z * ga + be);
        t[c4*4+3][row] = f2bf(v.w * ga + be);
    }
    __syncthreads();
#pragma unroll
    for (int rep = 0; rep < 2; ++rep) {
        int lin = rep * 256 + tid;         // 512 = 64 hw-rows x 8 groups
        int row = lin >> 3;                // hw_local
        int u8  = lin & 7;
        unsigned short* dst = h + (((size_t)(b*4096 + hw0 + row)) << 9) + c0 + u8*8;
        *(short8*)dst = *(const short8*)&t[row][u8*8];
    }
}

// ---------------- 128x128 bf16 MFMA GEMM, C[m,n] = sum_k A[m,k]*B[n,k], K=512 ----
// mode 0: out bf16 [M x 512],  out[m*512+n]  = bf16((acc + bias[n]) * scale)   (q/k)
// mode 1: out bf16 [512 x 32768], out[m*32768+n] = bf16(acc + bias[m])         (vT)
// mode 2: out fp32 d_out[b][m][hw], n = b*4096+hw: acc + bias[m] + resid[addr] (o-proj)
__global__ __launch_bounds__(256, 2) void gemm_bt(const unsigned short* __restrict__ A,
                                                  const unsigned short* __restrict__ B,
                                                  const float* __restrict__ bias,
                                                  const float* __restrict__ resid,
                                                  void* __restrict__ out,
                                                  int mode, float scale) {
    __shared__ unsigned short As[128][40], Bs[128][40];  // 32-col K-slab, pad 40
    int m0 = blockIdx.y * 128, n0 = blockIdx.x * 128;
    int tid = threadIdx.x, w = tid >> 6, l = tid & 63;
    int lr = l & 15, lk = (l >> 4) * 8;
    int rbase = (w >> 1) * 64, cbase = (w & 1) * 64;
    f32x4 acc[4][4] = {};
    for (int k0 = 0; k0 < 512; k0 += 32) {
        __syncthreads();
#pragma unroll
        for (int p = 0; p < 2; ++p) {
            int lin = p * 256 + tid;
            int r = lin >> 2, qq = lin & 3;
            *(short8*)&As[r][qq*8] = *(const short8*)(A + (size_t)(m0 + r)*512 + k0 + qq*8);
            *(short8*)&Bs[r][qq*8] = *(const short8*)(B + (size_t)(n0 + r)*512 + k0 + qq*8);
        }
        __syncthreads();
        short8 af[4], bf[4];
#pragma unroll
        for (int i = 0; i < 4; ++i) {
            af[i] = *(const short8*)&As[rbase + i*16 + lr][lk];
            bf[i] = *(const short8*)&Bs[cbase + i*16 + lr][lk];
        }
#pragma unroll
        for (int i = 0; i < 4; ++i)
#pragma unroll
            for (int j = 0; j < 4; ++j)
                acc[i][j] = __builtin_amdgcn_mfma_f32_16x16x32_bf16(af[i], bf[j], acc[i][j], 0, 0, 0);
    }
    // epilogue: C row = 4*(l>>4)+r, col = l&15
    int lq4 = (l >> 4) * 4;
#pragma unroll
    for (int i = 0; i < 4; ++i) {
        int rowg = m0 + rbase + i*16 + lq4;
#pragma unroll
        for (int j = 0; j < 4; ++j) {
            int colg = n0 + cbase + j*16 + lr;
#pragma unroll
            for (int r = 0; r < 4; ++r) {
                float v = acc[i][j][r];
                int rr = rowg + r;
                if (mode == 0) {
                    ((unsigned short*)out)[(size_t)rr * 512 + colg] = f2bf((v + bias[colg]) * scale);
                } else if (mode == 1) {
                    ((unsigned short*)out)[(size_t)rr * 32768 + colg] = f2bf(v + bias[rr]);
                } else {
                    size_t addr = ((size_t)(colg >> 12)) * 2097152 + (size_t)rr * 4096 + (colg & 4095);
                    ((float*)out)[addr] = v + bias[rr] + resid[addr];
                }
            }
        }
    }
}

// ---------------- streaming-softmax attention (no max-sub; scores are small) ----
// q (alpha folded), k: [B*4096, 512] bf16;  vt: [512, 32768] bf16;  o: [B*4096,512] bf16
__global__ __launch_bounds__(256, 2) void flash(const unsigned short* __restrict__ q,
                                                const unsigned short* __restrict__ k,
                                                const unsigned short* __restrict__ vt,
                                                unsigned short* __restrict__ o) {
    __shared__ unsigned short Qc[64][40];    // [q-row][32 d]   5.1 KB
    __shared__ unsigned short Kc[128][40];   // [k-pos][32 d]  10.2 KB
    __shared__ unsigned short P[64][136];    // [q-row][128 pos] 17.4 KB
    __shared__ unsigned short Vc[64][136];   // [d][128 pos]   17.4 KB
    __shared__ float lbuf[64];
    int b = blockIdx.y, q0 = blockIdx.x * 64;
    int tid = threadIdx.x, w = tid >> 6, l = tid & 63;
    int lr = l & 15, lq = l >> 4, lk = lq * 8;
    const unsigned short* qb = q + ((size_t)(b*4096 + q0)) * 512;
    const unsigned short* kb = k + ((size_t)b*4096) * 512;
    const unsigned short* vb = vt + (size_t)b * 4096;      // row c at vb + c*32768
    f32x4 acc_o[8][4] = {};   // [d-chunk of 64][nt] -> 128 VGPRs
    float lpart[2][4] = {};   // streaming row-sum partials (this wave's cols)
    int srow = (w >> 1) * 32, scol = (w & 1) * 64;  // S wave-tile 32x64

    for (int kt = 0; kt < 4096; kt += 128) {
        // ---- S = q' k^T for tile [64 q x 128 pos], K=512 in 32-wide slabs ----
        f32x4 sacc[2][4] = {};
        for (int k0 = 0; k0 < 512; k0 += 32) {
            __syncthreads();
            {
                int r = tid >> 2, qq = tid & 3;  // 64 rows x 4 x 16B
                *(short8*)&Qc[r][qq*8] = *(const short8*)(qb + (size_t)r*512 + k0 + qq*8);
            }
#pragma unroll
            for (int p = 0; p < 2; ++p) {
                int lin = p * 256 + tid;
                int r = lin >> 2, qq = lin & 3;
                *(short8*)&Kc[r][qq*8] = *(const short8*)(kb + (size_t)(kt + r)*512 + k0 + qq*8);
            }
            __syncthreads();
            short8 af[2], bfr[4];
#pragma unroll
            for (int i = 0; i < 2; ++i) af[i] = *(const short8*)&Qc[srow + i*16 + lr][lk];
#pragma unroll
            for (int j = 0; j < 4; ++j) bfr[j] = *(const short8*)&Kc[scol + j*16 + lr][lk];
#pragma unroll
            for (int i = 0; i < 2; ++i)
#pragma unroll
                for (int j = 0; j < 4; ++j)
                    sacc[i][j] = __builtin_amdgcn_mfma_f32_16x16x32_bf16(af[i], bfr[j], sacc[i][j], 0, 0, 0);
        }
        __syncthreads();
        // ---- P = exp(S) (fp32), accumulate row-sums, write P to LDS as bf16 ----
#pragma unroll
        for (int i = 0; i < 2; ++i)
#pragma unroll
            for (int j = 0; j < 4; ++j)
#pragma unroll
                for (int r = 0; r < 4; ++r) {
                    float e = __expf(sacc[i][j][r]);
                    lpart[i][r] += e;
                    P[srow + i*16 + lq*4 + r][scol + j*16 + lr] = f2bf(e);
                }
        __syncthreads();
        // ---- O += P * V ; wave w owns q-rows 16w..16w+15, all 512 d ----
        short8 pa[4];
#pragma unroll
        for (int ks = 0; ks < 4; ++ks) pa[ks] = *(const short8*)&P[w*16 + lr][ks*32 + lk];
        for (int d0 = 0; d0 < 512; d0 += 64) {
            __syncthreads();
#pragma unroll
            for (int p = 0; p < 4; ++p) {
                int lin = p * 256 + tid;          // 64 d-rows x 16 x 16B
                int r = lin >> 4, sx = lin & 15;
                *(short8*)&Vc[r][sx*8] = *(const short8*)(vb + (size_t)(d0 + r)*32768 + kt + sx*8);
            }
            __syncthreads();
            int ch = d0 >> 6;
#pragma unroll
            for (int j = 0; j < 4; ++j)
#pragma unroll
                for (int ks = 0; ks < 4; ++ks) {
                    short8 vf = *(const short8*)&Vc[j*16 + lr][ks*32 + lk];
                    acc_o[ch][j] = __builtin_amdgcn_mfma_f32_16x16x32_bf16(pa[ks], vf, acc_o[ch][j], 0, 0, 0);
                }
        }
    }
    // ---- reduce row sums across lanes/waves, normalize, store ----
    __syncthreads();
    if (tid < 64) lbuf[tid] = 0.f;
    __syncthreads();
#pragma unroll
    for (int i = 0; i < 2; ++i)
#pragma unroll
        for (int r = 0; r < 4; ++r) {
            float v = lpart[i][r];
            v += __shfl_xor(v, 1); v += __shfl_xor(v, 2);
            v += __shfl_xor(v, 4); v += __shfl_xor(v, 8);
            if (lr == 0) atomicAdd(&lbuf[srow + i*16 + lq*4 + r], v);
        }
    __syncthreads();
    float rl[4];
#pragma unroll
    for (int r = 0; r < 4; ++r) rl[r] = 1.0f / lbuf[w*16 + lq*4 + r];
    unsigned short* ob = o + ((size_t)(b*4096 + q0)) * 512;
#pragma unroll
    for (int ch = 0; ch < 8; ++ch)
#pragma unroll
        for (int j = 0; j < 4; ++j)
#pragma unroll
            for (int r = 0; r < 4; ++r) {
                int rowl = w*16 + lq*4 + r;
                int col = ch*64 + j*16 + lr;
                ob[(size_t)rowl*512 + col] = f2bf(acc_o[ch][j][r] * rl[r]);
            }
}

extern "C" void kernel_launch(void* const* d_in, const int* in_sizes, int n_in,
                              void* d_out, int out_size, void* d_ws, size_t ws_size,
                              hipStream_t stream) {
    const float* x     = (const float*)d_in[0];
    const float* gamma = (const float*)d_in[1];
    const float* beta  = (const float*)d_in[2];
    const float* wq = (const float*)d_in[3];  const float* bq = (const float*)d_in[4];
    const float* wk = (const float*)d_in[5];  const float* bk = (const float*)d_in[6];
    const float* wv = (const float*)d_in[7];  const float* bv = (const float*)d_in[8];
    const float* wo = (const float*)d_in[9];  const float* bo = (const float*)d_in[10];

    // workspace layout (needs ~130 MiB)
    char* w = (char*)d_ws;
    float* stats        = (float*)w;                    //   2 KB
    unsigned short* wqb = (unsigned short*)(w + 2048);  // 512 KB each
    unsigned short* wkb = wqb + 262144;
    unsigned short* wvb = wkb + 262144;
    unsigned short* wob = wvb + 262144;
    unsigned short* h   = wob + 262144;                 // 32 MB  [B*HW, C] bf16
    unsigned short* qb  = h  + 33554432/2;              // 32 MB
    unsigned short* kb  = qb + 33554432/2;              // 32 MB
    unsigned short* vtb = kb + 33554432/2;              // 32 MB  [C, B*HW] bf16
    unsigned short* ob  = h;                            // alias: h dead after vT GEMM

    gn_stats<<<256, 256, 0, stream>>>(x, stats);
    wcvt<<<256, 256, 0, stream>>>(wq, wqb);
    wcvt<<<256, 256, 0, stream>>>(wk, wkb);
    wcvt<<<256, 256, 0, stream>>>(wv, wvb);
    wcvt<<<256, 256, 0, stream>>>(wo, wob);
    gn_apply<<<dim3(64, 8, 8), 256, 0, stream>>>(x, stats, gamma, beta, h);
    // q = alpha*(h wq^T + bq), k = h wk^T + bk  : [32768 x 512]
    gemm_bt<<<dim3(4, 256), 256, 0, stream>>>(h, wqb, bq, nullptr, qb, 0, ALPHA);
    gemm_bt<<<dim3(4, 256), 256, 0, stream>>>(h, wkb, bk, nullptr, kb, 0, 1.0f);
    // vT[c, pos] = wv h^T + bv : [512 x 32768]
    gemm_bt<<<dim3(256, 4), 256, 0, stream>>>(wvb, h, bv, nullptr, vtb, 1, 1.0f);
    flash<<<dim3(64, 8), 256, 0, stream>>>(qb, kb, vtb, ob);
    // out[b,c,hw] = wo o^T + bo + x
    gemm_bt<<<dim3(256, 4), 256, 0, stream>>>(wob, ob, bo, x, d_out, 2, 1.0f);
}

// Round 3
// 960.385 us; speedup vs baseline: 1.2604x; 1.2604x over previous
//
#include <hip/hip_runtime.h>
#include <hip/hip_bf16.h>

// B=8, C=512, G=32, HW=4096. All matrix dims are multiples of 128 -> no guards.
typedef __attribute__((ext_vector_type(8))) short short8;
typedef __attribute__((ext_vector_type(4))) float f32x4;

#define ALPHA 0.044194173824159216f

__device__ __forceinline__ unsigned short f2bf(float f) {
    union { float f; unsigned int u; } c; c.f = f;
    unsigned int u = c.u;
    return (unsigned short)((u + 0x7FFFu + ((u >> 16) & 1u)) >> 16);
}

// ---------------- GroupNorm stats: one block per (b,g), 16ch x 4096 contiguous ----
__global__ __launch_bounds__(256) void gn_stats(const float* __restrict__ x,
                                                float* __restrict__ stats) {
    int blk = blockIdx.x;  // b*32 + g
    const float4* src = (const float4*)(x + (size_t)blk * 65536);
    float s = 0.f, sq = 0.f;
    for (int i = threadIdx.x; i < 16384; i += 256) {
        float4 v = src[i];
        s  += v.x + v.y + v.z + v.w;
        sq += v.x*v.x + v.y*v.y + v.z*v.z + v.w*v.w;
    }
    for (int off = 32; off; off >>= 1) {
        s  += __shfl_down(s, off);
        sq += __shfl_down(sq, off);
    }
    __shared__ float ss[4], ssq[4];
    int wid = threadIdx.x >> 6;
    if ((threadIdx.x & 63) == 0) { ss[wid] = s; ssq[wid] = sq; }
    __syncthreads();
    if (threadIdx.x == 0) {
        float S = ss[0]+ss[1]+ss[2]+ss[3], Q = ssq[0]+ssq[1]+ssq[2]+ssq[3];
        float mu = S * (1.f/65536.f);
        float var = Q * (1.f/65536.f) - mu*mu;
        stats[blk] = mu;
        stats[256 + blk] = rsqrtf(var + 1e-6f);
    }
}

// ---------------- weight fp32 -> bf16 ----------------
__global__ __launch_bounds__(256) void wcvt(const float* __restrict__ s,
                                            unsigned short* __restrict__ d) {
    int i = blockIdx.x * 1024 + threadIdx.x * 4;
    float4 v = *(const float4*)(s + i);
    ushort4 o = make_ushort4(f2bf(v.x), f2bf(v.y), f2bf(v.z), f2bf(v.w));
    *(ushort4*)(d + i) = o;
}

// ---------------- zero the softmax-denominator accumulator ----------------
__global__ __launch_bounds__(256) void zero_l(float* __restrict__ l) {
    ((float4*)l)[blockIdx.x * 256 + threadIdx.x] = make_float4(0.f, 0.f, 0.f, 0.f);
}

// ------- GN apply + transpose: x[b][c][hw] fp32 -> h[(b*4096+hw)][c] bf16 -------
__global__ __launch_bounds__(256) void gn_apply(const float* __restrict__ x,
                                                const float* __restrict__ stats,
                                                const float* __restrict__ gamma,
                                                const float* __restrict__ beta,
                                                unsigned short* __restrict__ h) {
    __shared__ unsigned short t[64][72];  // [hw_local][c_local], pad 72
    int b = blockIdx.z, c0 = blockIdx.y * 64, hw0 = blockIdx.x * 64;
    int tid = threadIdx.x;
#pragma unroll
    for (int rep = 0; rep < 4; ++rep) {
        int lin = rep * 256 + tid;         // 1024 = 64 c-rows x 16 float4
        int row = lin >> 4;                // c_local
        int c4  = lin & 15;                // float4 idx along hw
        int c   = c0 + row;
        const float4* src = (const float4*)(x + ((size_t)(b*512 + c) << 12) + hw0);
        float4 v = src[c4];
        int sidx = b*32 + (c >> 4);
        float mu = stats[sidx], rs = stats[256 + sidx];
        float ga = gamma[c] * rs, be = beta[c] - mu * ga;
        t[c4*4+0][row] = f2bf(v.x * ga + be);
        t[c4*4+1][row] = f2bf(v.y * ga + be);
        t[c4*4+2][row] = f2bf(v.z * ga + be);
        t[c4*4+3][row] = f2bf(v.w * ga + be);
    }
    __syncthreads();
#pragma unroll
    for (int rep = 0; rep < 2; ++rep) {
        int lin = rep * 256 + tid;         // 512 = 64 hw-rows x 8 groups
        int row = lin >> 3;                // hw_local
        int u8  = lin & 7;
        unsigned short* dst = h + (((size_t)(b*4096 + hw0 + row)) << 9) + c0 + u8*8;
        *(short8*)dst = *(const short8*)&t[row][u8*8];
    }
}

// ---------------- universal 128x128 bf16 MFMA GEMM, BK=64 ----------------
// C[m,n] = sum_k A[m,k] * B[n,k]   (A: lda-strided rows, B: ldb-strided rows)
// z = blockIdx.z selects batch: A += z*aZs, B += z*bZs, out += z*oZs, lout += z*4096
// mode 0: out bf16, out[m*ldo+n] = bf16((acc + bias[n]) * scale)          (q/k proj)
// mode 1: out bf16, out[m*ldo+n] = bf16(acc + bias[m])                    (vT proj)
// mode 2: out fp32 d_out[b][m][hw], n = b*4096+hw:
//           acc/lvec[n] + bias[m] + resid                                 (o-proj)
// mode 3: out bf16 P[m*ldo+n] = bf16(exp(acc)); atomicAdd row sums to lout (S pass)
// mode 4: out bf16, out[m*ldo+n] = bf16(acc)                              (P*V pass)
__global__ __launch_bounds__(256, 2) void gemm_bt(const unsigned short* __restrict__ A,
                                                  int lda, long aZs,
                                                  const unsigned short* __restrict__ B,
                                                  int ldb, long bZs,
                                                  const float* __restrict__ bias,
                                                  const float* __restrict__ resid,
                                                  const float* __restrict__ lvec,
                                                  float* __restrict__ lout,
                                                  void* __restrict__ out,
                                                  long ldo, long oZs,
                                                  int K, int mode, float scale) {
    __shared__ unsigned short As[128][72], Bs[128][72];  // 64-wide K-slab, pad 72
    int z = blockIdx.z;
    A += (size_t)z * aZs;
    B += (size_t)z * bZs;
    unsigned short* outu = (unsigned short*)out + (size_t)z * oZs;
    if (lout) lout += (size_t)z * 4096;
    int m0 = blockIdx.y * 128, n0 = blockIdx.x * 128;
    int tid = threadIdx.x, w = tid >> 6, l = tid & 63;
    int lr = l & 15, lq = l >> 4, lk = lq * 8;
    int rbase = (w >> 1) * 64, cbase = (w & 1) * 64;
    f32x4 acc[4][4] = {};
    for (int k0 = 0; k0 < K; k0 += 64) {
        __syncthreads();
#pragma unroll
        for (int p = 0; p < 4; ++p) {
            int lin = p * 256 + tid;           // 1024 = 128 rows x 8 short8
            int r = lin >> 3, qq = lin & 7;
            *(short8*)&As[r][qq*8] = *(const short8*)(A + (size_t)(m0 + r)*lda + k0 + qq*8);
            *(short8*)&Bs[r][qq*8] = *(const short8*)(B + (size_t)(n0 + r)*ldb + k0 + qq*8);
        }
        __syncthreads();
        short8 af[4][2], bfv[4][2];
#pragma unroll
        for (int i = 0; i < 4; ++i)
#pragma unroll
            for (int ks = 0; ks < 2; ++ks) {
                af[i][ks]  = *(const short8*)&As[rbase + i*16 + lr][ks*32 + lk];
                bfv[i][ks] = *(const short8*)&Bs[cbase + i*16 + lr][ks*32 + lk];
            }
#pragma unroll
        for (int ks = 0; ks < 2; ++ks)
#pragma unroll
            for (int i = 0; i < 4; ++i)
#pragma unroll
                for (int j = 0; j < 4; ++j)
                    acc[i][j] = __builtin_amdgcn_mfma_f32_16x16x32_bf16(af[i][ks], bfv[j][ks], acc[i][j], 0, 0, 0);
    }
    // epilogue: C row = 4*lq + r (within 16-tile), col = lr
    int lq4 = lq * 4;
    if (mode == 3) {
#pragma unroll
        for (int i = 0; i < 4; ++i) {
            int rowl = rbase + i*16 + lq4;
#pragma unroll
            for (int r = 0; r < 4; ++r) {
                float s = 0.f;
#pragma unroll
                for (int j = 0; j < 4; ++j) {
                    float e = __expf(acc[i][j][r]);
                    s += e;
                    outu[(size_t)(m0 + rowl + r) * ldo + n0 + cbase + j*16 + lr] = f2bf(e);
                }
                s += __shfl_xor(s, 1); s += __shfl_xor(s, 2);
                s += __shfl_xor(s, 4); s += __shfl_xor(s, 8);
                if (lr == 0) atomicAdd(&lout[m0 + rowl + r], s);
            }
        }
        return;
    }
#pragma unroll
    for (int i = 0; i < 4; ++i) {
        int rowg = m0 + rbase + i*16 + lq4;
#pragma unroll
        for (int j = 0; j < 4; ++j) {
            int colg = n0 + cbase + j*16 + lr;
#pragma unroll
            for (int r = 0; r < 4; ++r) {
                float v = acc[i][j][r];
                int rr = rowg + r;
                if (mode == 0) {
                    outu[(size_t)rr * ldo + colg] = f2bf((v + bias[colg]) * scale);
                } else if (mode == 1) {
                    outu[(size_t)rr * ldo + colg] = f2bf(v + bias[rr]);
                } else if (mode == 4) {
                    outu[(size_t)rr * ldo + colg] = f2bf(v);
                } else {
                    size_t addr = ((size_t)(colg >> 12)) * 2097152 + (size_t)rr * 4096 + (colg & 4095);
                    ((float*)out)[addr] = v / lvec[colg] + bias[rr] + resid[addr];
                }
            }
        }
    }
}

extern "C" void kernel_launch(void* const* d_in, const int* in_sizes, int n_in,
                              void* d_out, int out_size, void* d_ws, size_t ws_size,
                              hipStream_t stream) {
    const float* x     = (const float*)d_in[0];
    const float* gamma = (const float*)d_in[1];
    const float* beta  = (const float*)d_in[2];
    const float* wq = (const float*)d_in[3];  const float* bq = (const float*)d_in[4];
    const float* wk = (const float*)d_in[5];  const float* bk = (const float*)d_in[6];
    const float* wv = (const float*)d_in[7];  const float* bv = (const float*)d_in[8];
    const float* wo = (const float*)d_in[9];  const float* bo = (const float*)d_in[10];

    // ---- workspace layout: base part identical to the PROVEN round-0 130.2 MiB ----
    char* wsp = (char*)d_ws;
    float* stats        = (float*)wsp;                    //   2 KB
    unsigned short* wqb = (unsigned short*)(wsp + 2048);  // 512 KB each
    unsigned short* wkb = wqb + 262144;
    unsigned short* wvb = wkb + 262144;
    unsigned short* wob = wvb + 262144;
    unsigned short* h   = wob + 262144;                   // 32 MB [B*HW, C] bf16
    unsigned short* qb  = h  + 16777216;                  // 32 MB
    unsigned short* kb  = qb + 16777216;                  // 32 MB
    unsigned short* vtb = kb + 16777216;                  // 32 MB [C, B*HW] bf16
    float* lbuf         = (float*)(vtb + 16777216);       // 128 KB softmax denoms
    unsigned short* PbWs= (unsigned short*)(lbuf + 32768);// big path only: 128 MB
    unsigned short* ob  = h;                              // alias: h dead after vT GEMM

    // big path needs 2048 + 2MB + 128MB + 128KB + 128MB = 270,665,728 bytes
    const bool big = ws_size >= 272000000ull;

    gn_stats<<<256, 256, 0, stream>>>(x, stats);
    wcvt<<<256, 256, 0, stream>>>(wq, wqb);
    wcvt<<<256, 256, 0, stream>>>(wk, wkb);
    wcvt<<<256, 256, 0, stream>>>(wv, wvb);
    wcvt<<<256, 256, 0, stream>>>(wo, wob);
    gn_apply<<<dim3(64, 8, 8), 256, 0, stream>>>(x, stats, gamma, beta, h);
    zero_l<<<32, 256, 0, stream>>>(lbuf);

    // q = alpha*(h wq^T + bq), k = h wk^T + bk  : [32768 x 512]
    gemm_bt<<<dim3(4, 256), 256, 0, stream>>>(h, 512, 0, wqb, 512, 0, bq, nullptr, nullptr, nullptr,
                                              qb, 512, 0, 512, 0, ALPHA);
    gemm_bt<<<dim3(4, 256), 256, 0, stream>>>(h, 512, 0, wkb, 512, 0, bk, nullptr, nullptr, nullptr,
                                              kb, 512, 0, 512, 0, 1.0f);
    // vT[c, pos] = wv h^T + bv : [512 x 32768]
    gemm_bt<<<dim3(256, 4), 256, 0, stream>>>(wvb, 512, 0, h, 512, 0, bv, nullptr, nullptr, nullptr,
                                              vtb, 32768, 0, 512, 1, 1.0f);

    if (big) {
        // ---- P (128 MB) in workspace; 2 chunks x 4 batches; PV at 512 blocks ----
        for (int c = 0; c < 2; ++c) {
            size_t c4 = (size_t)c * 4;
            gemm_bt<<<dim3(32, 32, 4), 256, 0, stream>>>(
                qb + c4 * 4096 * 512, 512, (long)4096 * 512,
                kb + c4 * 4096 * 512, 512, (long)4096 * 512,
                nullptr, nullptr, nullptr, lbuf + c4 * 4096,
                PbWs, 4096, (long)4096 * 4096, 512, 3, 1.0f);
            gemm_bt<<<dim3(4, 32, 4), 256, 0, stream>>>(
                PbWs, 4096, (long)4096 * 4096,
                vtb + c4 * 4096, 32768, (long)4096,
                nullptr, nullptr, nullptr, nullptr,
                ob + c4 * 4096 * 512, 512, (long)4096 * 512, 4096, 4, 1.0f);
        }
    } else {
        // ---- P (64 MB = 2 batches bf16) lives in d_out; 4 chunks x 2 batches ----
        unsigned short* PbOut = (unsigned short*)d_out;
        for (int c = 0; c < 4; ++c) {
            size_t c2 = (size_t)c * 2;
            gemm_bt<<<dim3(32, 32, 2), 256, 0, stream>>>(
                qb + c2 * 4096 * 512, 512, (long)4096 * 512,
                kb + c2 * 4096 * 512, 512, (long)4096 * 512,
                nullptr, nullptr, nullptr, lbuf + c2 * 4096,
                PbOut, 4096, (long)4096 * 4096, 512, 3, 1.0f);
            gemm_bt<<<dim3(4, 32, 2), 256, 0, stream>>>(
                PbOut, 4096, (long)4096 * 4096,
                vtb + c2 * 4096, 32768, (long)4096,
                nullptr, nullptr, nullptr, nullptr,
                ob + c2 * 4096 * 512, 512, (long)4096 * 512, 4096, 4, 1.0f);
        }
    }
    // out[b,c,hw] = (wo o_unnorm^T)/l + bo + x   (overwrites all of d_out)
    gemm_bt<<<dim3(256, 4), 256, 0, stream>>>(wob, 512, 0, ob, 512, 0, bo, x, lbuf, nullptr,
                                              d_out, 0, 0, 512, 2, 1.0f);
}

// Round 4
// 915.851 us; speedup vs baseline: 1.3217x; 1.0486x over previous
//
#include <hip/hip_runtime.h>
#include <hip/hip_bf16.h>

// B=8, C=512, G=32, HW=4096. All matrix dims are multiples of 128 -> no guards.
typedef __attribute__((ext_vector_type(8))) short short8;
typedef __attribute__((ext_vector_type(4))) float f32x4;

#define ALPHA 0.044194173824159216f

__device__ __forceinline__ unsigned short f2bf(float f) {
    union { float f; unsigned int u; } c; c.f = f;
    unsigned int u = c.u;
    return (unsigned short)((u + 0x7FFFu + ((u >> 16) & 1u)) >> 16);
}

// ---------------- GroupNorm stats: one block per (b,g), 16ch x 4096 contiguous ----
__global__ __launch_bounds__(256) void gn_stats(const float* __restrict__ x,
                                                float* __restrict__ stats) {
    int blk = blockIdx.x;  // b*32 + g
    const float4* src = (const float4*)(x + (size_t)blk * 65536);
    float s = 0.f, sq = 0.f;
    for (int i = threadIdx.x; i < 16384; i += 256) {
        float4 v = src[i];
        s  += v.x + v.y + v.z + v.w;
        sq += v.x*v.x + v.y*v.y + v.z*v.z + v.w*v.w;
    }
    for (int off = 32; off; off >>= 1) {
        s  += __shfl_down(s, off);
        sq += __shfl_down(sq, off);
    }
    __shared__ float ss[4], ssq[4];
    int wid = threadIdx.x >> 6;
    if ((threadIdx.x & 63) == 0) { ss[wid] = s; ssq[wid] = sq; }
    __syncthreads();
    if (threadIdx.x == 0) {
        float S = ss[0]+ss[1]+ss[2]+ss[3], Q = ssq[0]+ssq[1]+ssq[2]+ssq[3];
        float mu = S * (1.f/65536.f);
        float var = Q * (1.f/65536.f) - mu*mu;
        stats[blk] = mu;
        stats[256 + blk] = rsqrtf(var + 1e-6f);
    }
}

// ---------------- weight fp32 -> bf16 ----------------
__global__ __launch_bounds__(256) void wcvt(const float* __restrict__ s,
                                            unsigned short* __restrict__ d) {
    int i = blockIdx.x * 1024 + threadIdx.x * 4;
    float4 v = *(const float4*)(s + i);
    ushort4 o = make_ushort4(f2bf(v.x), f2bf(v.y), f2bf(v.z), f2bf(v.w));
    *(ushort4*)(d + i) = o;
}

// ---------------- zero the softmax-denominator accumulator ----------------
__global__ __launch_bounds__(256) void zero_l(float* __restrict__ l) {
    ((float4*)l)[blockIdx.x * 256 + threadIdx.x] = make_float4(0.f, 0.f, 0.f, 0.f);
}

// ------- GN apply + transpose: x[b][c][hw] fp32 -> h[(b*4096+hw)][c] bf16 -------
__global__ __launch_bounds__(256) void gn_apply(const float* __restrict__ x,
                                                const float* __restrict__ stats,
                                                const float* __restrict__ gamma,
                                                const float* __restrict__ beta,
                                                unsigned short* __restrict__ h) {
    __shared__ unsigned short t[64][72];  // [hw_local][c_local], pad 72
    int b = blockIdx.z, c0 = blockIdx.y * 64, hw0 = blockIdx.x * 64;
    int tid = threadIdx.x;
#pragma unroll
    for (int rep = 0; rep < 4; ++rep) {
        int lin = rep * 256 + tid;         // 1024 = 64 c-rows x 16 float4
        int row = lin >> 4;                // c_local
        int c4  = lin & 15;                // float4 idx along hw
        int c   = c0 + row;
        const float4* src = (const float4*)(x + ((size_t)(b*512 + c) << 12) + hw0);
        float4 v = src[c4];
        int sidx = b*32 + (c >> 4);
        float mu = stats[sidx], rs = stats[256 + sidx];
        float ga = gamma[c] * rs, be = beta[c] - mu * ga;
        t[c4*4+0][row] = f2bf(v.x * ga + be);
        t[c4*4+1][row] = f2bf(v.y * ga + be);
        t[c4*4+2][row] = f2bf(v.z * ga + be);
        t[c4*4+3][row] = f2bf(v.w * ga + be);
    }
    __syncthreads();
#pragma unroll
    for (int rep = 0; rep < 2; ++rep) {
        int lin = rep * 256 + tid;         // 512 = 64 hw-rows x 8 groups
        int row = lin >> 3;                // hw_local
        int u8  = lin & 7;
        unsigned short* dst = h + (((size_t)(b*4096 + hw0 + row)) << 9) + c0 + u8*8;
        *(short8*)dst = *(const short8*)&t[row][u8*8];
    }
}

// ---------------- universal 128x128 bf16 MFMA GEMM, BK=64 ----------------
// C[m,n] = sum_k A[m,k] * B[n,k]
// mode 0: out bf16, out[m*ldo+n] = bf16((acc + bias[n]) * scale)          (q/k proj)
// mode 1: out bf16, out[m*ldo+n] = bf16(acc + bias[m])                    (vT proj)
// mode 2: out fp32 d_out[b][m][hw], n = b*4096+hw:
//           acc/lvec[n] + bias[m] + resid                                 (o-proj)
// mode 3: out bf16 P[m*ldo+n] = bf16(exp(acc)); atomicAdd row sums to lout (S pass)
__global__ __launch_bounds__(256, 2) void gemm_bt(const unsigned short* __restrict__ A,
                                                  int lda, long aZs,
                                                  const unsigned short* __restrict__ B,
                                                  int ldb, long bZs,
                                                  const float* __restrict__ bias,
                                                  const float* __restrict__ resid,
                                                  const float* __restrict__ lvec,
                                                  float* __restrict__ lout,
                                                  void* __restrict__ out,
                                                  long ldo, long oZs,
                                                  int K, int mode, float scale) {
    __shared__ unsigned short As[128][72], Bs[128][72];  // 64-wide K-slab, pad 72
    int z = blockIdx.z;
    A += (size_t)z * aZs;
    B += (size_t)z * bZs;
    unsigned short* outu = (unsigned short*)out + (size_t)z * oZs;
    if (lout) lout += (size_t)z * 4096;
    int m0 = blockIdx.y * 128, n0 = blockIdx.x * 128;
    int tid = threadIdx.x, w = tid >> 6, l = tid & 63;
    int lr = l & 15, lq = l >> 4, lk = lq * 8;
    int rbase = (w >> 1) * 64, cbase = (w & 1) * 64;
    f32x4 acc[4][4] = {};
    for (int k0 = 0; k0 < K; k0 += 64) {
        __syncthreads();
#pragma unroll
        for (int p = 0; p < 4; ++p) {
            int lin = p * 256 + tid;           // 1024 = 128 rows x 8 short8
            int r = lin >> 3, qq = lin & 7;
            *(short8*)&As[r][qq*8] = *(const short8*)(A + (size_t)(m0 + r)*lda + k0 + qq*8);
            *(short8*)&Bs[r][qq*8] = *(const short8*)(B + (size_t)(n0 + r)*ldb + k0 + qq*8);
        }
        __syncthreads();
        short8 af[4][2], bfv[4][2];
#pragma unroll
        for (int i = 0; i < 4; ++i)
#pragma unroll
            for (int ks = 0; ks < 2; ++ks) {
                af[i][ks]  = *(const short8*)&As[rbase + i*16 + lr][ks*32 + lk];
                bfv[i][ks] = *(const short8*)&Bs[cbase + i*16 + lr][ks*32 + lk];
            }
#pragma unroll
        for (int ks = 0; ks < 2; ++ks)
#pragma unroll
            for (int i = 0; i < 4; ++i)
#pragma unroll
                for (int j = 0; j < 4; ++j)
                    acc[i][j] = __builtin_amdgcn_mfma_f32_16x16x32_bf16(af[i][ks], bfv[j][ks], acc[i][j], 0, 0, 0);
    }
    // epilogue: C row = 4*lq + r (within 16-tile), col = lr
    int lq4 = lq * 4;
    if (mode == 3) {
#pragma unroll
        for (int i = 0; i < 4; ++i) {
            int rowl = rbase + i*16 + lq4;
#pragma unroll
            for (int r = 0; r < 4; ++r) {
                float s = 0.f;
#pragma unroll
                for (int j = 0; j < 4; ++j) {
                    float e = __expf(acc[i][j][r]);
                    s += e;
                    outu[(size_t)(m0 + rowl + r) * ldo + n0 + cbase + j*16 + lr] = f2bf(e);
                }
                s += __shfl_xor(s, 1); s += __shfl_xor(s, 2);
                s += __shfl_xor(s, 4); s += __shfl_xor(s, 8);
                if (lr == 0) atomicAdd(&lout[m0 + rowl + r], s);
            }
        }
        return;
    }
#pragma unroll
    for (int i = 0; i < 4; ++i) {
        int rowg = m0 + rbase + i*16 + lq4;
#pragma unroll
        for (int j = 0; j < 4; ++j) {
            int colg = n0 + cbase + j*16 + lr;
#pragma unroll
            for (int r = 0; r < 4; ++r) {
                float v = acc[i][j][r];
                int rr = rowg + r;
                if (mode == 0) {
                    outu[(size_t)rr * ldo + colg] = f2bf((v + bias[colg]) * scale);
                } else if (mode == 1) {
                    outu[(size_t)rr * ldo + colg] = f2bf(v + bias[rr]);
                } else {
                    size_t addr = ((size_t)(colg >> 12)) * 2097152 + (size_t)rr * 4096 + (colg & 4095);
                    ((float*)out)[addr] = v / lvec[colg] + bias[rr] + resid[addr];
                }
            }
        }
    }
}

// ---------------- P*V pass: 128x64 tiles, 4 blocks/CU ----------------
// o_unnorm[(zofs+z)*4096 + m][n] = sum_k P[z][m][k] * vt[n][(zofs+z)*4096 + k]
// P batches 0,1 at P0 (+z*16M), batches 2,3 at P1 (+(z-2)*16M).
__global__ __launch_bounds__(256, 4) void gemm_pv(const unsigned short* __restrict__ P0,
                                                  const unsigned short* __restrict__ P1,
                                                  const unsigned short* __restrict__ vt,
                                                  unsigned short* __restrict__ o,
                                                  int zofs) {
    __shared__ unsigned short As[128][72], Bs[64][72];   // 27.6 KB
    int z = blockIdx.z;
    const unsigned short* A = (z < 2) ? P0 + (size_t)z * 16777216
                                      : P1 + (size_t)(z - 2) * 16777216;
    int zb = zofs + z;
    const unsigned short* vb = vt + (size_t)zb * 4096;
    int m0 = blockIdx.y * 128, n0 = blockIdx.x * 64;
    int tid = threadIdx.x, w = tid >> 6, l = tid & 63;
    int lr = l & 15, lq = l >> 4, lk = lq * 8;
    int rbase = w * 32;                                   // wave: 32 rows x 64 cols
    f32x4 acc[2][4] = {};
    for (int k0 = 0; k0 < 4096; k0 += 64) {
        __syncthreads();
#pragma unroll
        for (int p = 0; p < 4; ++p) {
            int lin = p * 256 + tid;            // 1024 = 128 rows x 8 short8
            int r = lin >> 3, qq = lin & 7;
            *(short8*)&As[r][qq*8] = *(const short8*)(A + (size_t)(m0 + r)*4096 + k0 + qq*8);
        }
#pragma unroll
        for (int p = 0; p < 2; ++p) {
            int lin = p * 256 + tid;            // 512 = 64 rows x 8 short8
            int r = lin >> 3, qq = lin & 7;
            *(short8*)&Bs[r][qq*8] = *(const short8*)(vb + (size_t)(n0 + r)*32768 + k0 + qq*8);
        }
        __syncthreads();
        short8 af[2][2], bfv[4][2];
#pragma unroll
        for (int i = 0; i < 2; ++i)
#pragma unroll
            for (int ks = 0; ks < 2; ++ks)
                af[i][ks] = *(const short8*)&As[rbase + i*16 + lr][ks*32 + lk];
#pragma unroll
        for (int j = 0; j < 4; ++j)
#pragma unroll
            for (int ks = 0; ks < 2; ++ks)
                bfv[j][ks] = *(const short8*)&Bs[j*16 + lr][ks*32 + lk];
#pragma unroll
        for (int ks = 0; ks < 2; ++ks)
#pragma unroll
            for (int i = 0; i < 2; ++i)
#pragma unroll
                for (int j = 0; j < 4; ++j)
                    acc[i][j] = __builtin_amdgcn_mfma_f32_16x16x32_bf16(af[i][ks], bfv[j][ks], acc[i][j], 0, 0, 0);
    }
    unsigned short* ob = o + ((size_t)zb * 4096 + m0) * 512 + n0;
    int lq4 = lq * 4;
#pragma unroll
    for (int i = 0; i < 2; ++i)
#pragma unroll
        for (int j = 0; j < 4; ++j)
#pragma unroll
            for (int r = 0; r < 4; ++r)
                ob[(size_t)(rbase + i*16 + lq4 + r) * 512 + j*16 + lr] = f2bf(acc[i][j][r]);
}

extern "C" void kernel_launch(void* const* d_in, const int* in_sizes, int n_in,
                              void* d_out, int out_size, void* d_ws, size_t ws_size,
                              hipStream_t stream) {
    const float* x     = (const float*)d_in[0];
    const float* gamma = (const float*)d_in[1];
    const float* beta  = (const float*)d_in[2];
    const float* wq = (const float*)d_in[3];  const float* bq = (const float*)d_in[4];
    const float* wk = (const float*)d_in[5];  const float* bk = (const float*)d_in[6];
    const float* wv = (const float*)d_in[7];  const float* bv = (const float*)d_in[8];
    const float* wo = (const float*)d_in[9];  const float* bo = (const float*)d_in[10];

    // ---- base workspace layout (proven, ends at 136,448,000 B) ----
    char* wsp = (char*)d_ws;
    float* stats        = (float*)wsp;                    //   2 KB
    unsigned short* wqb = (unsigned short*)(wsp + 2048);  // 512 KB each
    unsigned short* wkb = wqb + 262144;
    unsigned short* wvb = wkb + 262144;
    unsigned short* wob = wvb + 262144;
    unsigned short* h   = wob + 262144;                   // 32 MB [B*HW, C] bf16
    unsigned short* qb  = h  + 16777216;                  // 32 MB
    unsigned short* kb  = qb + 16777216;                  // 32 MB
    unsigned short* vtb = kb + 16777216;                  // 32 MB [C, B*HW] bf16
    float* lbuf         = (float*)(vtb + 16777216);       // 128 KB softmax denoms
    unsigned short* Pw  = (unsigned short*)(lbuf + 32768);// mid path: +64 MB, ends 203.6 MB
    unsigned short* Pd  = (unsigned short*)d_out;         // 64 MB: 2 batches of P
    unsigned short* ob  = h;                              // alias: h dead after vT GEMM

    // mid path needs 203,556,864 B total
    const bool mid = ws_size >= 204000000ull;

    gn_stats<<<256, 256, 0, stream>>>(x, stats);
    wcvt<<<256, 256, 0, stream>>>(wq, wqb);
    wcvt<<<256, 256, 0, stream>>>(wk, wkb);
    wcvt<<<256, 256, 0, stream>>>(wv, wvb);
    wcvt<<<256, 256, 0, stream>>>(wo, wob);
    gn_apply<<<dim3(64, 8, 8), 256, 0, stream>>>(x, stats, gamma, beta, h);
    zero_l<<<32, 256, 0, stream>>>(lbuf);

    // q = alpha*(h wq^T + bq), k = h wk^T + bk  : [32768 x 512]
    gemm_bt<<<dim3(4, 256), 256, 0, stream>>>(h, 512, 0, wqb, 512, 0, bq, nullptr, nullptr, nullptr,
                                              qb, 512, 0, 512, 0, ALPHA);
    gemm_bt<<<dim3(4, 256), 256, 0, stream>>>(h, 512, 0, wkb, 512, 0, bk, nullptr, nullptr, nullptr,
                                              kb, 512, 0, 512, 0, 1.0f);
    // vT[c, pos] = wv h^T + bv : [512 x 32768]
    gemm_bt<<<dim3(256, 4), 256, 0, stream>>>(wvb, 512, 0, h, 512, 0, bv, nullptr, nullptr, nullptr,
                                              vtb, 32768, 0, 512, 1, 1.0f);

    const long QS = (long)4096 * 512;   // per-batch q/k/o stride
    const long PS = (long)4096 * 4096;  // per-batch P stride
    if (mid) {
        // ---- 2 chunks x 4 batches: P in d_out (2) + ws tail (2); PV at 1024 blocks ----
        for (int c = 0; c < 2; ++c) {
            size_t z0 = (size_t)c * 4;
            gemm_bt<<<dim3(32, 32, 2), 256, 0, stream>>>(
                qb + z0 * QS, 512, QS, kb + z0 * QS, 512, QS,
                nullptr, nullptr, nullptr, lbuf + z0 * 4096,
                Pd, 4096, PS, 512, 3, 1.0f);
            gemm_bt<<<dim3(32, 32, 2), 256, 0, stream>>>(
                qb + (z0 + 2) * QS, 512, QS, kb + (z0 + 2) * QS, 512, QS,
                nullptr, nullptr, nullptr, lbuf + (z0 + 2) * 4096,
                Pw, 4096, PS, 512, 3, 1.0f);
            gemm_pv<<<dim3(8, 32, 4), 256, 0, stream>>>(Pd, Pw, vtb, ob, (int)z0);
        }
    } else {
        // ---- 4 chunks x 2 batches: P in d_out only; PV at 512 blocks ----
        for (int c = 0; c < 4; ++c) {
            size_t z0 = (size_t)c * 2;
            gemm_bt<<<dim3(32, 32, 2), 256, 0, stream>>>(
                qb + z0 * QS, 512, QS, kb + z0 * QS, 512, QS,
                nullptr, nullptr, nullptr, lbuf + z0 * 4096,
                Pd, 4096, PS, 512, 3, 1.0f);
            gemm_pv<<<dim3(8, 32, 2), 256, 0, stream>>>(Pd, Pd, vtb, ob, (int)z0);
        }
    }
    // out[b,c,hw] = (wo o_unnorm^T)/l + bo + x   (overwrites all of d_out)
    gemm_bt<<<dim3(256, 4), 256, 0, stream>>>(wob, 512, 0, ob, 512, 0, bo, x, lbuf, nullptr,
                                              d_out, 0, 0, 512, 2, 1.0f);
}